// Round 6
// baseline (806.299 us; speedup 1.0000x reference)
//
#include <hip/hip_runtime.h>

// ADI diffusion B=16, C=8, S=128, 10 steps, in-place in d_out.
// Round 6: single plain-launched kernel, 21 phases, 20 SOFTWARE global
// barriers (one-shot counters in d_ws, agent-scope atomics). 256 blocks x
// 256 threads: co-residency guaranteed (grid <= CU count, block fits CU),
// so the spin barrier cannot deadlock. Jacobi-2 replaces Thomas (contraction
// ~1e-3). Thread owns 32 elems = 8 channels x 4 points -> channel mix is a
// register-level matvec (no LDS, no sync). LDS only for Jacobi neighbors.

constexpr int S_ = 128;
constexpr float EPSF = 1e-6f;
constexpr unsigned NBLK = 256;

__device__ __forceinline__ void gbar(unsigned* __restrict__ bar, int slot) {
    __syncthreads();
    if (threadIdx.x == 0) {
        __hip_atomic_fetch_add(&bar[slot], 1u, __ATOMIC_ACQ_REL, __HIP_MEMORY_SCOPE_AGENT);
        while (__hip_atomic_load(&bar[slot], __ATOMIC_ACQUIRE, __HIP_MEMORY_SCOPE_AGENT) < NBLK) { }
    }
    __syncthreads();
}

// Jacobi (x0 + 2 iters) along w. p = tid + 256k; w = p & 127. d[] holds the
// rhs on entry, the solution on exit. Trailing sync protects sU reuse.
__device__ __forceinline__ void jacobi_w(float* __restrict__ sU, int tid,
                                         const float (&co)[32], const float (&rb)[32],
                                         float (&d)[32]) {
    float x[32];
    #pragma unroll
    for (int k = 0; k < 32; ++k) { x[k] = rb[k] * d[k]; sU[tid + 256 * k] = x[k]; }
    __syncthreads();
    #pragma unroll
    for (int k = 0; k < 32; ++k) {
        const int p = tid + 256 * k, w = p & 127;
        const float xl = (w > 0)   ? sU[p - 1] : 0.f;
        const float xr = (w < 127) ? sU[p + 1] : 0.f;
        x[k] = rb[k] * fmaf(co[k], xl + xr, d[k]);
    }
    __syncthreads();
    #pragma unroll
    for (int k = 0; k < 32; ++k) sU[tid + 256 * k] = x[k];
    __syncthreads();
    #pragma unroll
    for (int k = 0; k < 32; ++k) {
        const int p = tid + 256 * k, w = p & 127;
        const float xl = (w > 0)   ? sU[p - 1] : 0.f;
        const float xr = (w < 127) ? sU[p + 1] : 0.f;
        d[k] = rb[k] * fmaf(co[k], xl + xr, d[k]);
    }
    __syncthreads();
}

// Jacobi along h for the y phase. p = tid + 256k; h = p >> 6, wl = p & 63.
__device__ __forceinline__ void jacobi_h(float* __restrict__ sU, int tid,
                                         const float (&co)[32], const float (&rb)[32],
                                         float (&d)[32]) {
    float x[32];
    #pragma unroll
    for (int k = 0; k < 32; ++k) { x[k] = rb[k] * d[k]; sU[tid + 256 * k] = x[k]; }
    __syncthreads();
    #pragma unroll
    for (int k = 0; k < 32; ++k) {
        const int p = tid + 256 * k, h = p >> 6;
        const float xl = (h > 0)   ? sU[p - 64] : 0.f;
        const float xr = (h < 127) ? sU[p + 64] : 0.f;
        x[k] = rb[k] * fmaf(co[k], xl + xr, d[k]);
    }
    __syncthreads();
    #pragma unroll
    for (int k = 0; k < 32; ++k) sU[tid + 256 * k] = x[k];
    __syncthreads();
    #pragma unroll
    for (int k = 0; k < 32; ++k) {
        const int p = tid + 256 * k, h = p >> 6;
        const float xl = (h > 0)   ? sU[p - 64] : 0.f;
        const float xr = (h < 127) ? sU[p + 64] : 0.f;
        d[k] = rb[k] * fmaf(co[k], xl + xr, d[k]);
    }
    __syncthreads();
}

// x phase: block = (b, 8-row h slab). p = tid+256k -> c = p>>10,
// hh = (p>>7)&7, w = p&127. Thread-local k = c*4 + j <-> (c, pt = tid+256j).
template <bool PRE, bool MIX, bool POST>
__device__ __forceinline__ void xphase(
    float* __restrict__ sU, const float* __restrict__ sM,
    const float* __restrict__ usrc, float* __restrict__ udst,
    const float* __restrict__ ab, const float* __restrict__ atc, float t)
{
    const int tid = threadIdx.x;
    const int b  = blockIdx.x >> 4;
    const int h0 = (blockIdx.x & 15) << 3;

    float d[32], co[32], rb[32];
    #pragma unroll
    for (int k = 0; k < 32; ++k) {
        const int p = tid + 256 * k;
        const int w = p & 127, hh = (p >> 7) & 7, c = p >> 10;
        d[k] = usrc[((size_t)(b * 8 + c) * S_ + (h0 + hh)) * S_ + w];
        const int ga = (c * S_ + h0 + hh) * S_ + w;
        float al = fmaf(atc[ga], t, ab[ga]);
        al = fminf(fmaxf(al, EPSF), 10.f);
        const float cc = al * 0.0005f;          // * (dt/2)/dx^2
        co[k] = cc;
        rb[k] = __builtin_amdgcn_rcpf(
            fmaf((w == 0 || w == 127) ? 1.f : 2.f, cc, 1.f) + EPSF);
    }

    if (PRE) jacobi_w(sU, tid, co, rb, d);

    if (MIX) {
        #pragma unroll
        for (int j = 0; j < 4; ++j) {           // pure register matvec
            float o[8];
            #pragma unroll
            for (int dd = 0; dd < 8; ++dd) {
                float acc = 0.f;
                #pragma unroll
                for (int c = 0; c < 8; ++c) acc = fmaf(sM[dd * 8 + c], d[c * 4 + j], acc);
                o[dd] = acc;
            }
            #pragma unroll
            for (int dd = 0; dd < 8; ++dd) d[dd * 4 + j] = o[dd];
        }
    }

    if (POST) jacobi_w(sU, tid, co, rb, d);     // same t -> same co/rb

    #pragma unroll
    for (int k = 0; k < 32; ++k) {
        const int p = tid + 256 * k;
        const int w = p & 127, hh = (p >> 7) & 7, c = p >> 10;
        udst[((size_t)(b * 8 + c) * S_ + (h0 + hh)) * S_ + w] = d[k];
    }
}

// y phase: block = (bc, 64-wide w half). p = tid+256k -> h = p>>6, wl = p&63.
__device__ __forceinline__ void yphase(
    float* __restrict__ sU, float* __restrict__ u,
    const float* __restrict__ bbeta, const float* __restrict__ btc, float t)
{
    const int tid = threadIdx.x;
    const int bc = blockIdx.x >> 1;
    const int c  = bc & 7;
    const int w0 = (blockIdx.x & 1) << 6;

    float d[32], co[32], rb[32];
    #pragma unroll
    for (int k = 0; k < 32; ++k) {
        const int p = tid + 256 * k;
        const int wl = p & 63, h = p >> 6;
        d[k] = u[((size_t)bc * S_ + h) * S_ + w0 + wl];
        const int ga = (c * S_ + h) * S_ + w0 + wl;
        float be = fmaf(btc[ga], t, bbeta[ga]);
        be = fminf(fmaxf(be, EPSF), 10.f);
        const float cc = be * 0.001f;           // * dt/dy^2
        co[k] = cc;
        rb[k] = __builtin_amdgcn_rcpf(
            fmaf((h == 0 || h == 127) ? 1.f : 2.f, cc, 1.f) + EPSF);
    }

    jacobi_h(sU, tid, co, rb, d);

    #pragma unroll
    for (int k = 0; k < 32; ++k) {
        const int p = tid + 256 * k;
        const int wl = p & 63, h = p >> 6;
        u[((size_t)bc * S_ + h) * S_ + w0 + wl] = d[k];
    }
}

__global__ __launch_bounds__(256, 1) void fused_kernel(
    const float* __restrict__ u_in, float* __restrict__ u,
    const float* __restrict__ ab, const float* __restrict__ bbeta,
    const float* __restrict__ atc, const float* __restrict__ btc,
    const float* __restrict__ cm, unsigned* __restrict__ bar)
{
    __shared__ float sU[8192];   // 32 KB
    __shared__ float sM[64];

    if (threadIdx.x < 64) sM[threadIdx.x] = cm[threadIdx.x];
    __syncthreads();

    int slot = 0;
    // step-0 head: mix + x half (t=0), reads pristine input, fills d_out
    xphase<false, true, true>(sU, sM, u_in, u, ab, atc, 0.f);
    gbar(bar, slot++);

    for (int k = 0; k < 10; ++k) {
        const float ty = (float)((2 * k + 1) * 0.0005);
        yphase(sU, u, bbeta, btc, ty);
        gbar(bar, slot++);
        const float tx = (float)((2 * k + 2) * 0.0005);
        if (k < 9) {
            // trailing x of step k + mix + leading x of step k+1 (same t)
            xphase<true, true, true>(sU, sM, u, u, ab, atc, tx);
            gbar(bar, slot++);
        } else {
            xphase<true, false, false>(sU, sM, u, u, ab, atc, tx);
        }
    }
}

extern "C" void kernel_launch(void* const* d_in, const int* in_sizes, int n_in,
                              void* d_out, int out_size, void* d_ws, size_t ws_size,
                              hipStream_t stream) {
    const float* u_in = (const float*)d_in[0];
    const float* ab   = (const float*)d_in[1];
    const float* bbta = (const float*)d_in[2];
    const float* atc  = (const float*)d_in[3];
    const float* btc  = (const float*)d_in[4];
    const float* cm   = (const float*)d_in[5];
    float* u = (float*)d_out;
    unsigned* bar = (unsigned*)d_ws;

    // zero the 20 barrier slots (d_ws is re-poisoned before every call)
    hipMemsetAsync(bar, 0, 32 * sizeof(unsigned), stream);
    fused_kernel<<<dim3(256), dim3(256), 0, stream>>>(u_in, u, ab, bbta, atc, btc, cm, bar);
}

// Round 7
// 724.877 us; speedup vs baseline: 1.1123x; 1.1123x over previous
//
#include <hip/hip_runtime.h>

// ADI diffusion B=16, C=8, S=128, 10 steps, in-place in d_out.
// Round 7: identical phase structure to round 6 (single plain launch, 21
// phases, software global barrier, Jacobi-2, register-level channel mix).
// Fix: the round-6 barrier spun on an ACQUIRE atomic load -> one L2
// invalidate PER POLL (buffer_inv storm, 557 GB/s effective, 737 us).
// Now: relaxed spin + s_sleep, exactly one release fence (L2 writeback)
// before the increment and one acquire fence (L2 invalidate) after the spin.

constexpr int S_ = 128;
constexpr float EPSF = 1e-6f;
constexpr unsigned NBLK = 256;

__device__ __forceinline__ void gbar(unsigned* __restrict__ bar, int slot) {
    __syncthreads();
    if (threadIdx.x == 0) {
        __builtin_amdgcn_fence(__ATOMIC_RELEASE, "agent");   // one L2 writeback
        __hip_atomic_fetch_add(&bar[slot], 1u, __ATOMIC_RELAXED, __HIP_MEMORY_SCOPE_AGENT);
        while (__hip_atomic_load(&bar[slot], __ATOMIC_RELAXED, __HIP_MEMORY_SCOPE_AGENT) < NBLK)
            __builtin_amdgcn_s_sleep(8);
        __builtin_amdgcn_fence(__ATOMIC_ACQUIRE, "agent");   // one L2 invalidate
    }
    __syncthreads();
}

// Jacobi (x0 + 2 iters) along w. p = tid + 256k; w = p & 127. d[] holds the
// rhs on entry, the solution on exit. Trailing sync protects sU reuse.
__device__ __forceinline__ void jacobi_w(float* __restrict__ sU, int tid,
                                         const float (&co)[32], const float (&rb)[32],
                                         float (&d)[32]) {
    float x[32];
    #pragma unroll
    for (int k = 0; k < 32; ++k) { x[k] = rb[k] * d[k]; sU[tid + 256 * k] = x[k]; }
    __syncthreads();
    #pragma unroll
    for (int k = 0; k < 32; ++k) {
        const int p = tid + 256 * k, w = p & 127;
        const float xl = (w > 0)   ? sU[p - 1] : 0.f;
        const float xr = (w < 127) ? sU[p + 1] : 0.f;
        x[k] = rb[k] * fmaf(co[k], xl + xr, d[k]);
    }
    __syncthreads();
    #pragma unroll
    for (int k = 0; k < 32; ++k) sU[tid + 256 * k] = x[k];
    __syncthreads();
    #pragma unroll
    for (int k = 0; k < 32; ++k) {
        const int p = tid + 256 * k, w = p & 127;
        const float xl = (w > 0)   ? sU[p - 1] : 0.f;
        const float xr = (w < 127) ? sU[p + 1] : 0.f;
        d[k] = rb[k] * fmaf(co[k], xl + xr, d[k]);
    }
    __syncthreads();
}

// Jacobi along h for the y phase. p = tid + 256k; h = p >> 6, wl = p & 63.
__device__ __forceinline__ void jacobi_h(float* __restrict__ sU, int tid,
                                         const float (&co)[32], const float (&rb)[32],
                                         float (&d)[32]) {
    float x[32];
    #pragma unroll
    for (int k = 0; k < 32; ++k) { x[k] = rb[k] * d[k]; sU[tid + 256 * k] = x[k]; }
    __syncthreads();
    #pragma unroll
    for (int k = 0; k < 32; ++k) {
        const int p = tid + 256 * k, h = p >> 6;
        const float xl = (h > 0)   ? sU[p - 64] : 0.f;
        const float xr = (h < 127) ? sU[p + 64] : 0.f;
        x[k] = rb[k] * fmaf(co[k], xl + xr, d[k]);
    }
    __syncthreads();
    #pragma unroll
    for (int k = 0; k < 32; ++k) sU[tid + 256 * k] = x[k];
    __syncthreads();
    #pragma unroll
    for (int k = 0; k < 32; ++k) {
        const int p = tid + 256 * k, h = p >> 6;
        const float xl = (h > 0)   ? sU[p - 64] : 0.f;
        const float xr = (h < 127) ? sU[p + 64] : 0.f;
        d[k] = rb[k] * fmaf(co[k], xl + xr, d[k]);
    }
    __syncthreads();
}

// x phase: block = (b, 8-row h slab). p = tid+256k -> c = p>>10,
// hh = (p>>7)&7, w = p&127. Thread-local k = c*4 + j <-> (c, pt = tid+256j).
template <bool PRE, bool MIX, bool POST>
__device__ __forceinline__ void xphase(
    float* __restrict__ sU, const float* __restrict__ sM,
    const float* __restrict__ usrc, float* __restrict__ udst,
    const float* __restrict__ ab, const float* __restrict__ atc, float t)
{
    const int tid = threadIdx.x;
    const int b  = blockIdx.x >> 4;
    const int h0 = (blockIdx.x & 15) << 3;

    float d[32], co[32], rb[32];
    #pragma unroll
    for (int k = 0; k < 32; ++k) {
        const int p = tid + 256 * k;
        const int w = p & 127, hh = (p >> 7) & 7, c = p >> 10;
        d[k] = usrc[((size_t)(b * 8 + c) * S_ + (h0 + hh)) * S_ + w];
        const int ga = (c * S_ + h0 + hh) * S_ + w;
        float al = fmaf(atc[ga], t, ab[ga]);
        al = fminf(fmaxf(al, EPSF), 10.f);
        const float cc = al * 0.0005f;          // * (dt/2)/dx^2
        co[k] = cc;
        rb[k] = __builtin_amdgcn_rcpf(
            fmaf((w == 0 || w == 127) ? 1.f : 2.f, cc, 1.f) + EPSF);
    }

    if (PRE) jacobi_w(sU, tid, co, rb, d);

    if (MIX) {
        #pragma unroll
        for (int j = 0; j < 4; ++j) {           // pure register matvec
            float o[8];
            #pragma unroll
            for (int dd = 0; dd < 8; ++dd) {
                float acc = 0.f;
                #pragma unroll
                for (int c = 0; c < 8; ++c) acc = fmaf(sM[dd * 8 + c], d[c * 4 + j], acc);
                o[dd] = acc;
            }
            #pragma unroll
            for (int dd = 0; dd < 8; ++dd) d[dd * 4 + j] = o[dd];
        }
    }

    if (POST) jacobi_w(sU, tid, co, rb, d);     // same t -> same co/rb

    #pragma unroll
    for (int k = 0; k < 32; ++k) {
        const int p = tid + 256 * k;
        const int w = p & 127, hh = (p >> 7) & 7, c = p >> 10;
        udst[((size_t)(b * 8 + c) * S_ + (h0 + hh)) * S_ + w] = d[k];
    }
}

// y phase: block = (bc, 64-wide w half). p = tid+256k -> h = p>>6, wl = p&63.
__device__ __forceinline__ void yphase(
    float* __restrict__ sU, float* __restrict__ u,
    const float* __restrict__ bbeta, const float* __restrict__ btc, float t)
{
    const int tid = threadIdx.x;
    const int bc = blockIdx.x >> 1;
    const int c  = bc & 7;
    const int w0 = (blockIdx.x & 1) << 6;

    float d[32], co[32], rb[32];
    #pragma unroll
    for (int k = 0; k < 32; ++k) {
        const int p = tid + 256 * k;
        const int wl = p & 63, h = p >> 6;
        d[k] = u[((size_t)bc * S_ + h) * S_ + w0 + wl];
        const int ga = (c * S_ + h) * S_ + w0 + wl;
        float be = fmaf(btc[ga], t, bbeta[ga]);
        be = fminf(fmaxf(be, EPSF), 10.f);
        const float cc = be * 0.001f;           // * dt/dy^2
        co[k] = cc;
        rb[k] = __builtin_amdgcn_rcpf(
            fmaf((h == 0 || h == 127) ? 1.f : 2.f, cc, 1.f) + EPSF);
    }

    jacobi_h(sU, tid, co, rb, d);

    #pragma unroll
    for (int k = 0; k < 32; ++k) {
        const int p = tid + 256 * k;
        const int wl = p & 63, h = p >> 6;
        u[((size_t)bc * S_ + h) * S_ + w0 + wl] = d[k];
    }
}

__global__ __launch_bounds__(256, 1) void fused_kernel(
    const float* __restrict__ u_in, float* __restrict__ u,
    const float* __restrict__ ab, const float* __restrict__ bbeta,
    const float* __restrict__ atc, const float* __restrict__ btc,
    const float* __restrict__ cm, unsigned* __restrict__ bar)
{
    __shared__ float sU[8192];   // 32 KB
    __shared__ float sM[64];

    if (threadIdx.x < 64) sM[threadIdx.x] = cm[threadIdx.x];
    __syncthreads();

    int slot = 0;
    // step-0 head: mix + x half (t=0), reads pristine input, fills d_out
    xphase<false, true, true>(sU, sM, u_in, u, ab, atc, 0.f);
    gbar(bar, slot++);

    for (int k = 0; k < 10; ++k) {
        const float ty = (float)((2 * k + 1) * 0.0005);
        yphase(sU, u, bbeta, btc, ty);
        gbar(bar, slot++);
        const float tx = (float)((2 * k + 2) * 0.0005);
        if (k < 9) {
            // trailing x of step k + mix + leading x of step k+1 (same t)
            xphase<true, true, true>(sU, sM, u, u, ab, atc, tx);
            gbar(bar, slot++);
        } else {
            xphase<true, false, false>(sU, sM, u, u, ab, atc, tx);
        }
    }
}

extern "C" void kernel_launch(void* const* d_in, const int* in_sizes, int n_in,
                              void* d_out, int out_size, void* d_ws, size_t ws_size,
                              hipStream_t stream) {
    const float* u_in = (const float*)d_in[0];
    const float* ab   = (const float*)d_in[1];
    const float* bbta = (const float*)d_in[2];
    const float* atc  = (const float*)d_in[3];
    const float* btc  = (const float*)d_in[4];
    const float* cm   = (const float*)d_in[5];
    float* u = (float*)d_out;
    unsigned* bar = (unsigned*)d_ws;

    // zero the 20 barrier slots (d_ws is re-poisoned before every call)
    hipMemsetAsync(bar, 0, 32 * sizeof(unsigned), stream);
    fused_kernel<<<dim3(256), dim3(256), 0, stream>>>(u_in, u, ab, bbta, atc, btc, cm, bar);
}

// Round 8
// 241.543 us; speedup vs baseline: 3.3381x; 3.0010x over previous
//
#include <hip/hip_runtime.h>

// ADI diffusion B=16, C=8, S=128, 10 steps.
// Round 8: halo fusion. Jacobi-2 has radius 2 along the sweep axis and
// x-solves/channel-mix are row-local, so one kernel per timestep does
//   [k==0 only: mix|x@0 tile-wide]  y@(k+1/2)  x@(k+1) mix x@(k+1)
// on an 8-row strip read with a 2-row halo (12-row tile). 10 launches
// instead of 21; buffers ping-pong d_out <-> d_ws to kill same-dispatch
// halo races. Thread owns 48 tile elems (all 8 channels of its points ->
// mixes are pure register matvecs); LDS = one 48 KB Jacobi exchange buffer.

constexpr int S_ = 128;
constexpr float EPSF = 1e-6f;

// w-direction Jacobi-2 on N elems/thread; elem k lives at LDS offset
// (half + 2k)*128 + w. Boundary masks depend only on w (uniform per thread).
// d[] = rhs in, solution out. Ends with a sync: sX free for reuse.
template <int N>
__device__ __forceinline__ void jacobi_w(float* __restrict__ sX, int half, int w,
                                         const float (&co)[N], const float (&rb)[N],
                                         float (&d)[N]) {
    float x[N];
    #pragma unroll
    for (int k = 0; k < N; ++k) { x[k] = rb[k] * d[k]; sX[(half + 2 * k) * S_ + w] = x[k]; }
    __syncthreads();
    #pragma unroll
    for (int k = 0; k < N; ++k) {
        const int L = (half + 2 * k) * S_ + w;
        const float xl = (w > 0)   ? sX[L - 1] : 0.f;
        const float xr = (w < 127) ? sX[L + 1] : 0.f;
        x[k] = rb[k] * fmaf(co[k], xl + xr, d[k]);
    }
    __syncthreads();
    #pragma unroll
    for (int k = 0; k < N; ++k) sX[(half + 2 * k) * S_ + w] = x[k];
    __syncthreads();
    #pragma unroll
    for (int k = 0; k < N; ++k) {
        const int L = (half + 2 * k) * S_ + w;
        const float xl = (w > 0)   ? sX[L - 1] : 0.f;
        const float xr = (w < 127) ? sX[L + 1] : 0.f;
        d[k] = rb[k] * fmaf(co[k], xl + xr, d[k]);
    }
    __syncthreads();
}

// Block = (b, 8-row strip). Tile = rows h0-2 .. h0+9 (out-of-range rows are
// zero: d=0, co=0 -> harmless). Thread elem k: idx = half+2k, c = idx/12,
// rt = idx%12, w = tid&127 (c/rt fold to constants per unrolled k).
template <bool HEAD, bool TAILMIX2>
__global__ __launch_bounds__(256, 1) void step_kernel(
    const float* __restrict__ usrc, float* __restrict__ udst,
    const float* __restrict__ ab, const float* __restrict__ atc,
    const float* __restrict__ bbeta, const float* __restrict__ btc,
    const float* __restrict__ cm, float t_y, float t_x)
{
    __shared__ float sX[96 * S_];   // 48 KB
    __shared__ float sM[64];

    const int tid  = threadIdx.x;
    const int b    = blockIdx.x >> 4;
    const int h0   = (blockIdx.x & 15) << 3;
    const int w    = tid & 127;
    const int half = tid >> 7;

    if (tid < 64) sM[tid] = cm[tid];

    // ---- tile load (12 rows x 8 c) ----
    float d[48];
    #pragma unroll
    for (int k = 0; k < 48; ++k) {
        const int c  = half ? (2 * k + 1) / 12 : (2 * k) / 12;
        const int rt = half ? (2 * k + 1) % 12 : (2 * k) % 12;
        const int gh = h0 - 2 + rt;
        const int ghc = min(max(gh, 0), S_ - 1);
        const float v = usrc[((b * 8 + c) * S_ + ghc) * S_ + w];
        d[k] = (gh >= 0 && gh < S_) ? v : 0.f;
    }

    if (HEAD) {
        __syncthreads();                      // sM visible
        // step-0 mix (register-local: thread holds all c for its rows)
        #pragma unroll
        for (int j = 0; j < 6; ++j) {         // rt = half + 2j, k = 6c + j
            float v[8], o[8];
            #pragma unroll
            for (int c = 0; c < 8; ++c) v[c] = d[6 * c + j];
            #pragma unroll
            for (int dd = 0; dd < 8; ++dd) {
                float acc = 0.f;
                #pragma unroll
                for (int c = 0; c < 8; ++c) acc = fmaf(sM[dd * 8 + c], v[c], acc);
                o[dd] = acc;
            }
            #pragma unroll
            for (int dd = 0; dd < 8; ++dd) d[6 * dd + j] = o[dd];
        }
        // x half @ t=0 tile-wide: alpha = clip(alpha_base)
        float cox[48], rbx[48];
        const float nbw = (w == 0 || w == 127) ? 1.f : 2.f;
        #pragma unroll
        for (int k = 0; k < 48; ++k) {
            const int c  = half ? (2 * k + 1) / 12 : (2 * k) / 12;
            const int rt = half ? (2 * k + 1) % 12 : (2 * k) % 12;
            const int gh = h0 - 2 + rt;
            const int ghc = min(max(gh, 0), S_ - 1);
            float al = ab[(c * S_ + ghc) * S_ + w];
            al = fminf(fmaxf(al, EPSF), 10.f);
            const float cc = (gh >= 0 && gh < S_) ? al * 0.0005f : 0.f;
            cox[k] = cc;
            rbx[k] = __builtin_amdgcn_rcpf(fmaf(nbw, cc, 1.f) + EPSF);
        }
        jacobi_w<48>(sX, half, w, cox, rbx, d);
    }

    // ---- y solve @ t_y (Jacobi-2 along h, valid for owned rows) ----
    {
        float coy[48], rby[48], x[48];
        #pragma unroll
        for (int k = 0; k < 48; ++k) {
            const int c  = half ? (2 * k + 1) / 12 : (2 * k) / 12;
            const int rt = half ? (2 * k + 1) % 12 : (2 * k) % 12;
            const int gh = h0 - 2 + rt;
            const int ghc = min(max(gh, 0), S_ - 1);
            const int gc = (c * S_ + ghc) * S_ + w;
            float be = fmaf(btc[gc], t_y, bbeta[gc]);
            be = fminf(fmaxf(be, EPSF), 10.f);
            const float cc = (gh >= 0 && gh < S_) ? be * 0.001f : 0.f;
            coy[k] = cc;
            const float nb = (gh == 0 || gh == S_ - 1) ? 1.f : 2.f;
            rby[k] = __builtin_amdgcn_rcpf(fmaf(nb, cc, 1.f) + EPSF);
        }
        #pragma unroll
        for (int k = 0; k < 48; ++k) { x[k] = rby[k] * d[k]; sX[(half + 2 * k) * S_ + w] = x[k]; }
        __syncthreads();
        #pragma unroll
        for (int k = 0; k < 48; ++k) {
            const int rt = half ? (2 * k + 1) % 12 : (2 * k) % 12;
            const int L = (half + 2 * k) * S_ + w;
            const float xl = (rt > 0)  ? sX[L - S_] : 0.f;
            const float xr = (rt < 11) ? sX[L + S_] : 0.f;
            x[k] = rby[k] * fmaf(coy[k], xl + xr, d[k]);
        }
        __syncthreads();
        #pragma unroll
        for (int k = 0; k < 48; ++k) sX[(half + 2 * k) * S_ + w] = x[k];
        __syncthreads();
        #pragma unroll
        for (int k = 0; k < 48; ++k) {
            const int rt = half ? (2 * k + 1) % 12 : (2 * k) % 12;
            const int L = (half + 2 * k) * S_ + w;
            const float xl = (rt > 0)  ? sX[L - S_] : 0.f;
            const float xr = (rt < 11) ? sX[L + S_] : 0.f;
            d[k] = rby[k] * fmaf(coy[k], xl + xr, d[k]);
        }
        __syncthreads();
        // publish y output (tile layout) for the ownership remap
        #pragma unroll
        for (int k = 0; k < 48; ++k) sX[(half + 2 * k) * S_ + w] = d[k];
        __syncthreads();
    }

    // ---- remap to owned rows; x@t_x | mix | x@t_x ----
    float dx[32], cox[32], rbx[32];
    {
        const float nbw = (w == 0 || w == 127) ? 1.f : 2.f;
        #pragma unroll
        for (int k = 0; k < 32; ++k) {
            const int idx2 = half + 2 * k;
            const int ro = idx2 & 7, c = idx2 >> 3;
            dx[k] = sX[(12 * c + ro + 2) * S_ + w];
            const int gc = (c * S_ + h0 + ro) * S_ + w;
            float al = fmaf(atc[gc], t_x, ab[gc]);
            al = fminf(fmaxf(al, EPSF), 10.f);
            const float cc = al * 0.0005f;
            cox[k] = cc;
            rbx[k] = __builtin_amdgcn_rcpf(fmaf(nbw, cc, 1.f) + EPSF);
        }
    }
    __syncthreads();                 // dx reads done before sX reuse
    jacobi_w<32>(sX, half, w, cox, rbx, dx);

    if (TAILMIX2) {
        #pragma unroll
        for (int j = 0; j < 4; ++j) {         // ro = half + 2j, k = 4c + j
            float v[8], o[8];
            #pragma unroll
            for (int c = 0; c < 8; ++c) v[c] = dx[4 * c + j];
            #pragma unroll
            for (int dd = 0; dd < 8; ++dd) {
                float acc = 0.f;
                #pragma unroll
                for (int c = 0; c < 8; ++c) acc = fmaf(sM[dd * 8 + c], v[c], acc);
                o[dd] = acc;
            }
            #pragma unroll
            for (int dd = 0; dd < 8; ++dd) dx[4 * dd + j] = o[dd];
        }
        jacobi_w<32>(sX, half, w, cox, rbx, dx);   // same t -> same coeffs
    }

    #pragma unroll
    for (int k = 0; k < 32; ++k) {
        const int idx2 = half + 2 * k;
        const int ro = idx2 & 7, c = idx2 >> 3;
        udst[((b * 8 + c) * S_ + h0 + ro) * S_ + w] = dx[k];
    }
}

extern "C" void kernel_launch(void* const* d_in, const int* in_sizes, int n_in,
                              void* d_out, int out_size, void* d_ws, size_t ws_size,
                              hipStream_t stream) {
    const float* u_in = (const float*)d_in[0];
    const float* ab   = (const float*)d_in[1];
    const float* bbta = (const float*)d_in[2];
    const float* atc  = (const float*)d_in[3];
    const float* btc  = (const float*)d_in[4];
    const float* cm   = (const float*)d_in[5];
    float* uo = (float*)d_out;
    float* uw = (float*)d_ws;     // 8 MB ping buffer (ws_size >= out bytes)

    const dim3 g(256), blk(256);
    const float dt2 = 0.0005f;

    // k=0: head(mix|x@0) + y@0.5 + x@1|mix|x@1, pristine input -> ws
    step_kernel<true, true><<<g, blk, 0, stream>>>(u_in, uw, ab, atc, bbta, btc, cm,
                                                   1 * dt2, 2 * dt2);
    const float* src = uw; float* dst = uo;
    for (int k = 1; k <= 8; ++k) {
        step_kernel<false, true><<<g, blk, 0, stream>>>(src, dst, ab, atc, bbta, btc, cm,
                                                        (2 * k + 1) * dt2, (2 * k + 2) * dt2);
        const float* ns = dst; dst = (dst == uo) ? uw : uo; src = ns;
    }
    // k=9: y@9.5 + x@10 (no mix) -> d_out (parity: src=uw, dst=uo)
    step_kernel<false, false><<<g, blk, 0, stream>>>(src, dst, ab, atc, bbta, btc, cm,
                                                     19 * dt2, 20 * dt2);
}

// Round 9
// 181.688 us; speedup vs baseline: 4.4378x; 1.3294x over previous
//
#include <hip/hip_runtime.h>

// ADI diffusion B=16, C=8, S=128, 10 steps. Round 9: register-run Jacobi.
// Jacobi-2 = fixed 5-point formula (e=rb*d, g=rb*co):
//   x1_i = e_i + g_i(e_{i-1}+e_{i+1}); x2_i = e_i + g_i(x1_{i-1}+x1_{i+1}).
// Thread owns runs of 8 (+2 halo) -> whole solve in registers, no LDS.
// LDS only re-layouts between phases (h-cols -> w-runs -> mix -> w-runs).
// 256 blocks x 512 threads (8 waves/CU). Row stride 129 + lane->row maps
// keep every LDS access <=2 lanes/bank. Ping-pong d_out <-> d_ws.

constexpr int S_ = 128;
constexpr int RS = 129;             // padded LDS row stride
constexpr float EPSF = 1e-6f;

// LDS regions (floats): A: head 96-row tile / owned 64-row tile
//                       B: head x@0 out / x1 out
//                       C: x-coeff (co) 64 rows
constexpr int OFF_A = 0;
constexpr int OFF_B = 12384;        // 96*129
constexpr int OFF_C = 24768;
constexpr int POOL  = 33024;        // ~129 KB

__device__ __forceinline__ void jrun(const float (&e)[12], const float (&g)[12],
                                     float (&o)[8]) {
    float x1[12];
    #pragma unroll
    for (int i = 1; i <= 10; ++i) x1[i] = fmaf(g[i], e[i - 1] + e[i + 1], e[i]);
    #pragma unroll
    for (int i = 2; i <= 9; ++i) o[i - 2] = fmaf(g[i], x1[i - 1] + x1[i + 1], e[i]);
}

template <bool HEAD, bool TAILMIX>
__global__ __launch_bounds__(512, 2) void step_kernel(
    const float* __restrict__ usrc, float* __restrict__ udst,
    const float* __restrict__ ab, const float* __restrict__ atc,
    const float* __restrict__ bbeta, const float* __restrict__ btc,
    const float* __restrict__ cm, float t_y, float t_x)
{
    __shared__ float sP[POOL];
    const int tid = threadIdx.x;
    const int b   = blockIdx.x >> 4;
    const int h0  = (blockIdx.x & 15) << 3;

    if (HEAD) {
        // load 12-row tile (col layout: lanes contiguous in w)
        #pragma unroll
        for (int m = 0; m < 2; ++m) {
            const int col = tid + 512 * m;
            const int c = col >> 7, w = col & 127;
            #pragma unroll
            for (int hh = 0; hh < 12; ++hh) {
                const int gh = h0 - 2 + hh;
                float v = 0.f;
                if (gh >= 0 && gh < S_) v = usrc[((b * 8 + c) * S_ + gh) * S_ + w];
                sP[OFF_A + (c * 12 + hh) * RS + w] = v;
            }
        }
        __syncthreads();
        // mix in place (each point owned by one thread)
        {
            float M[64];
            #pragma unroll
            for (int i = 0; i < 64; ++i) M[i] = cm[i];
            #pragma unroll
            for (int m = 0; m < 3; ++m) {
                const int p = tid + 512 * m;
                const int hh = p >> 7, w = p & 127;
                float v[8], o[8];
                #pragma unroll
                for (int c = 0; c < 8; ++c) v[c] = sP[OFF_A + (c * 12 + hh) * RS + w];
                #pragma unroll
                for (int dd = 0; dd < 8; ++dd) {
                    float a = 0.f;
                    #pragma unroll
                    for (int c = 0; c < 8; ++c) a = fmaf(M[dd * 8 + c], v[c], a);
                    o[dd] = a;
                }
                #pragma unroll
                for (int c = 0; c < 8; ++c) sP[OFF_A + (c * 12 + hh) * RS + w] = o[c];
            }
        }
        __syncthreads();
        // x@0 on 96 rows x 16 runs (alpha = clip(ab); scattered ab reads, head only)
        #pragma unroll
        for (int m = 0; m < 3; ++m) {
            const int run = tid + 512 * m;
            const int r96 = run % 96;
            const int wr  = run / 96;
            const int c = r96 / 12, hh = r96 % 12;
            const int gh = h0 - 2 + hh;
            const int w0 = wr * 8;
            const bool rowin = (gh >= 0 && gh < S_);
            float e[12], g[12];
            #pragma unroll
            for (int j = 0; j < 12; ++j) {
                const int wj = w0 - 2 + j;
                const bool win = (wj >= 0 && wj < S_);
                const float dv = win ? sP[OFF_A + r96 * RS + wj] : 0.f;
                float co = 0.f;
                if (rowin && win) {
                    float al = ab[(c * S_ + gh) * S_ + wj];
                    al = fminf(fmaxf(al, EPSF), 10.f);
                    co = al * 0.0005f;
                }
                const float nb = (wj == 0 || wj == S_ - 1) ? 1.f : 2.f;
                const float rb = __builtin_amdgcn_rcpf(fmaf(nb, co, 1.f) + EPSF);
                e[j] = rb * dv; g[j] = rb * co;
            }
            float o[8]; jrun(e, g, o);
            #pragma unroll
            for (int i = 0; i < 8; ++i) sP[OFF_B + r96 * RS + w0 + i] = o[i];
        }
        __syncthreads();
    }

    // ---- Y stage: 1024 (c,w) columns, 2/thread; solve along h in registers.
    #pragma unroll
    for (int m = 0; m < 2; ++m) {
        const int col = tid + 512 * m;
        const int c = col >> 7, w = col & 127;
        float e[12], g[12];
        #pragma unroll
        for (int hh = 0; hh < 12; ++hh) {
            const int gh = h0 - 2 + hh;
            const bool inr = (gh >= 0 && gh < S_);
            const int ghc = inr ? gh : 0;
            float dv;
            if (HEAD) dv = sP[OFF_B + (c * 12 + hh) * RS + w];
            else      dv = inr ? usrc[((b * 8 + c) * S_ + ghc) * S_ + w] : 0.f;
            const int gc = (c * S_ + ghc) * S_ + w;
            float be = fmaf(btc[gc], t_y, bbeta[gc]);
            be = fminf(fmaxf(be, EPSF), 10.f);
            const float co = inr ? be * 0.001f : 0.f;
            const float nb = (gh == 0 || gh == S_ - 1) ? 1.f : 2.f;
            const float rb = __builtin_amdgcn_rcpf(fmaf(nb, co, 1.f) + EPSF);
            e[hh] = rb * dv; g[hh] = rb * co;
        }
        float o[8]; jrun(e, g, o);
        #pragma unroll
        for (int i = 0; i < 8; ++i) sP[OFF_A + (c * 8 + i) * RS + w] = o[i];
    }
    // x-coeff into C (coalesced point layout)
    #pragma unroll
    for (int m = 0; m < 16; ++m) {
        const int p = tid + 512 * m;
        const int r = p >> 7, w = p & 127;
        const int c = r >> 3, ho = r & 7;
        const int gc = (c * S_ + h0 + ho) * S_ + w;
        float al = fmaf(atc[gc], t_x, ab[gc]);
        al = fminf(fmaxf(al, EPSF), 10.f);
        sP[OFF_C + r * RS + w] = al * 0.0005f;
    }
    __syncthreads();

    // ---- X1: 64 rows x 16 runs, 2/thread (lanes -> rows: conflict-free via RS=129)
    float rbk[2][12], gk[2][12], xo[2][8];
    #pragma unroll
    for (int m = 0; m < 2; ++m) {
        const int run = tid + 512 * m;
        const int r = run & 63, wr = run >> 6;
        const int w0 = wr * 8;
        float e[12];
        #pragma unroll
        for (int j = 0; j < 12; ++j) {
            const int wj = w0 - 2 + j;
            const bool win = (wj >= 0 && wj < S_);
            const float co = win ? sP[OFF_C + r * RS + wj] : 0.f;
            const float dv = win ? sP[OFF_A + r * RS + wj] : 0.f;
            const float nb = (wj == 0 || wj == S_ - 1) ? 1.f : 2.f;
            const float rb = __builtin_amdgcn_rcpf(fmaf(nb, co, 1.f) + EPSF);
            rbk[m][j] = rb; gk[m][j] = rb * co;
            e[j] = rb * dv;
        }
        jrun(e, gk[m], xo[m]);
    }

    if (TAILMIX) {
        #pragma unroll
        for (int m = 0; m < 2; ++m) {
            const int run = tid + 512 * m;
            const int r = run & 63, w0 = (run >> 6) * 8;
            #pragma unroll
            for (int i = 0; i < 8; ++i) sP[OFF_B + r * RS + w0 + i] = xo[m][i];
        }
        __syncthreads();
        // mix: 1024 points, 2/thread; read B, write A
        float M[64];
        #pragma unroll
        for (int i = 0; i < 64; ++i) M[i] = cm[i];
        #pragma unroll
        for (int m = 0; m < 2; ++m) {
            const int p = tid + 512 * m;
            const int ho = p >> 7, w = p & 127;
            float v[8], o[8];
            #pragma unroll
            for (int c = 0; c < 8; ++c) v[c] = sP[OFF_B + (c * 8 + ho) * RS + w];
            #pragma unroll
            for (int dd = 0; dd < 8; ++dd) {
                float a = 0.f;
                #pragma unroll
                for (int c = 0; c < 8; ++c) a = fmaf(M[dd * 8 + c], v[c], a);
                o[dd] = a;
            }
            #pragma unroll
            for (int c = 0; c < 8; ++c) sP[OFF_A + (c * 8 + ho) * RS + w] = o[c];
        }
        __syncthreads();
        // X2: same runs, same coeffs (same t)
        #pragma unroll
        for (int m = 0; m < 2; ++m) {
            const int run = tid + 512 * m;
            const int r = run & 63, wr = run >> 6;
            const int w0 = wr * 8;
            const int c = r >> 3, ho = r & 7;
            float e[12];
            #pragma unroll
            for (int j = 0; j < 12; ++j) {
                const int wj = w0 - 2 + j;
                const bool win = (wj >= 0 && wj < S_);
                const float dv = win ? sP[OFF_A + r * RS + wj] : 0.f;
                e[j] = rbk[m][j] * dv;
            }
            float o[8]; jrun(e, gk[m], o);
            float4* dst4 = (float4*)&udst[((b * 8 + c) * S_ + h0 + ho) * S_ + w0];
            dst4[0] = make_float4(o[0], o[1], o[2], o[3]);
            dst4[1] = make_float4(o[4], o[5], o[6], o[7]);
        }
    } else {
        #pragma unroll
        for (int m = 0; m < 2; ++m) {
            const int run = tid + 512 * m;
            const int r = run & 63, wr = run >> 6;
            const int w0 = wr * 8;
            const int c = r >> 3, ho = r & 7;
            float4* dst4 = (float4*)&udst[((b * 8 + c) * S_ + h0 + ho) * S_ + w0];
            dst4[0] = make_float4(xo[m][0], xo[m][1], xo[m][2], xo[m][3]);
            dst4[1] = make_float4(xo[m][4], xo[m][5], xo[m][6], xo[m][7]);
        }
    }
}

extern "C" void kernel_launch(void* const* d_in, const int* in_sizes, int n_in,
                              void* d_out, int out_size, void* d_ws, size_t ws_size,
                              hipStream_t stream) {
    const float* u_in = (const float*)d_in[0];
    const float* ab   = (const float*)d_in[1];
    const float* bbta = (const float*)d_in[2];
    const float* atc  = (const float*)d_in[3];
    const float* btc  = (const float*)d_in[4];
    const float* cm   = (const float*)d_in[5];
    float* uo = (float*)d_out;
    float* uw = (float*)d_ws;     // 8 MB ping buffer

    const dim3 g(256), blk(512);
    const float dt2 = 0.0005f;

    // k=0: head(mix|x@0) + y@0.5 + x@1|mix|x@1, pristine input -> ws
    step_kernel<true, true><<<g, blk, 0, stream>>>(u_in, uw, ab, atc, bbta, btc, cm,
                                                   1 * dt2, 2 * dt2);
    const float* src = uw; float* dst = uo;
    for (int k = 1; k <= 8; ++k) {
        step_kernel<false, true><<<g, blk, 0, stream>>>(src, dst, ab, atc, bbta, btc, cm,
                                                        (2 * k + 1) * dt2, (2 * k + 2) * dt2);
        const float* ns = dst; dst = (dst == uo) ? uw : uo; src = ns;
    }
    // k=9: y@9.5 + x@10 (no mix) -> d_out (parity: src=uw, dst=uo)
    step_kernel<false, false><<<g, blk, 0, stream>>>(src, dst, ab, atc, bbta, btc, cm,
                                                     19 * dt2, 20 * dt2);
}